// Round 9
// baseline (434.118 us; speedup 1.0000x reference)
//
#include <hip/hip_runtime.h>

#define N_NODE 100000
#define EMB 112
#define EMBP 128                      // padded bf16 row: 256 B, line-aligned
#define BATCH 512
#define SEQL 50
#define NNZ 1600000
#define NROWS (BATCH * SEQL)          // 25600 flattened session slots

#define NBUCK ((N_NODE + 63) / 64)    // 1563 buckets of 64 rows
#define BUCK_CAP 1536                 // mean 1024, sd 32 -> 16 sigma headroom
#define TILE_E 6272                   // 256 blocks x 1024 threads
#define P1_BLOCKS ((NNZ + TILE_E - 1) / TILE_E)   // 256

__device__ __forceinline__ float bf2f(unsigned short u) {
    return __uint_as_float((unsigned)u << 16);
}
__device__ __forceinline__ unsigned short f2bf(float f) {
    unsigned u = __float_as_uint(f);
    return (unsigned short)((u + 0x7FFF + ((u >> 16) & 1)) >> 16);   // RNE
}

// ---------------- prep: fp32 -> padded bf16 table + mark_needed ------------
__global__ __launch_bounds__(256) void prep(
    const float* __restrict__ in, unsigned short* __restrict__ out,
    const int* __restrict__ items, int* __restrict__ needed)
{
    int i = blockIdx.x * 256 + threadIdx.x;
    int r = i >> 5, c = i & 31;
    ushort4 o; o.x = 0; o.y = 0; o.z = 0; o.w = 0;
    if (c < 28) {
        float4 v = ((const float4*)in)[r * 28 + c];
        o.x = f2bf(v.x); o.y = f2bf(v.y); o.z = f2bf(v.z); o.w = f2bf(v.w);
    }
    ((ushort4*)out)[i] = o;
    if (i < NROWS) {
        int g = items[i];
        if (g > 0) needed[g - 1] = 1;   // benign races, all write 1
    }
}

// ---- phase 1: block-aggregated binning into 64-row bucket regions ---------
// 1024 threads/block for occupancy; one global reservation per (block,bucket).
__global__ __launch_bounds__(1024) void edge_bin(
    const int* __restrict__ rows, const int* __restrict__ cols,
    const float* __restrict__ vals,
    int* __restrict__ bcur, uint2* __restrict__ staged)
{
    __shared__ int hist[NBUCK];
    const int t = threadIdx.x;
    const int e0 = blockIdx.x * TILE_E;
    const int e1 = (e0 + TILE_E < NNZ) ? e0 + TILE_E : NNZ;

    for (int i = t; i < NBUCK; i += 1024) hist[i] = 0;
    __syncthreads();
    for (int e = e0 + t; e < e1; e += 1024)
        atomicAdd(&hist[rows[e] >> 6], 1);
    __syncthreads();
    for (int i = t; i < NBUCK; i += 1024) {
        int c = hist[i];
        hist[i] = (c > 0) ? atomicAdd(&bcur[i], c) : 0;
    }
    __syncthreads();
    for (int e = e0 + t; e < e1; e += 1024) {
        int r = rows[e];
        int b = r >> 6;
        int k = atomicAdd(&hist[b], 1);
        uint2 s;
        s.x = ((unsigned)(r & 63) << 26) | (unsigned)cols[e];
        s.y = __float_as_uint(vals[e]);
        staged[(size_t)b * BUCK_CAP + k] = s;
    }
}

// ---- phase 2: bucket-local CSR finalize, single staged read pass ----------
// Each thread caches its <=6 edges in registers between count and scatter.
__global__ __launch_bounds__(256) void bucket_build(
    const uint2* __restrict__ staged, const int* __restrict__ bcur,
    int2* __restrict__ csr_cv, int* __restrict__ row_start,
    int* __restrict__ counts)
{
    __shared__ int cnt[64];
    const int b = blockIdx.x;
    const int t = threadIdx.x;
    const int n = bcur[b];
    const size_t base = (size_t)b * BUCK_CAP;
    const int r0 = b << 6;

    uint2 my[BUCK_CAP / 256];
    int nm = 0;

    if (t < 64) cnt[t] = 0;
    __syncthreads();
    for (int i = t; i < n; i += 256) {
        uint2 s = staged[base + i];
        my[nm++] = s;
        atomicAdd(&cnt[s.x >> 26], 1);
    }
    __syncthreads();

    if (t < 64) {                       // wave 0: exclusive scan of 64 counts
        int c = cnt[t];
        int x = c;
        for (int o = 1; o < 64; o <<= 1) {
            int y = __shfl_up(x, o);
            if (t >= o) x += y;
        }
        int excl = x - c;
        int row = r0 + t;
        if (row < N_NODE) {
            row_start[row] = (int)base + excl;
            counts[row] = c;
        }
        cnt[t] = excl;                  // reuse as per-row cursor
    }
    __syncthreads();
    for (int j = 0; j < nm; ++j) {
        uint2 s = my[j];
        int rl = s.x >> 26;
        int k = atomicAdd(&cnt[rl], 1);
        int2 cv;
        cv.x = (int)(s.x & 0x03FFFFFFu);
        cv.y = (int)s.y;
        csr_cv[base + k] = cv;
    }
}

// ---------------- HyperConv layer: padded bf16 gather, 2 rows per wave -----
__global__ __launch_bounds__(256) void spmm_bf16(
    const unsigned short* __restrict__ src, const int2* __restrict__ csr_cv,
    const int* __restrict__ row_start, const int* __restrict__ counts,
    const int* __restrict__ needed, int use_needed,
    unsigned short* __restrict__ dst)
{
    const int lane = threadIdx.x & 63;
    const int wave = threadIdx.x >> 6;
    const int half = lane >> 5;
    const int hl = lane & 31;
    const int row = blockIdx.x * 8 + wave * 2 + half;   // grid covers N_NODE
    const int d0 = hl * 4;

    const bool skip = use_needed && (needed[row] == 0);
    int n = skip ? 0 : counts[row];
    const int beg = row_start[row];

    float a0 = 0.f, a1 = 0.f, a2 = 0.f, a3 = 0.f;
    int i = 0;
    for (; i + 8 <= n; i += 8) {
        #pragma unroll
        for (int j = 0; j < 8; ++j) {
            int2 cv = csr_cv[beg + i + j];
            float v = __int_as_float(cv.y);
            ushort4 u = *(const ushort4*)(src + (size_t)cv.x * EMBP + d0);
            a0 += v * bf2f(u.x);
            a1 += v * bf2f(u.y);
            a2 += v * bf2f(u.z);
            a3 += v * bf2f(u.w);
        }
    }
    for (; i < n; ++i) {
        int2 cv = csr_cv[beg + i];
        float v = __int_as_float(cv.y);
        ushort4 u = *(const ushort4*)(src + (size_t)cv.x * EMBP + d0);
        a0 += v * bf2f(u.x);
        a1 += v * bf2f(u.y);
        a2 += v * bf2f(u.z);
        a3 += v * bf2f(u.w);
    }
    if (!skip) {
        ushort4 o;
        o.x = f2bf(a0); o.y = f2bf(a1); o.z = f2bf(a2); o.w = f2bf(a3);
        *(ushort4*)(dst + (size_t)row * EMBP + d0) = o;
    }
}

// ---------------- gather + Q/K projection (register-tiled) -----------------
#define GP_ROWS 32
#define SEQ_PAD 116
__global__ __launch_bounds__(256) void gather_project(
    const float* __restrict__ emb0,
    const unsigned short* __restrict__ e1b, const unsigned short* __restrict__ e2b,
    const int* __restrict__ items,
    const float* __restrict__ Wq, const float* __restrict__ Wk,
    float* __restrict__ seqws, float* __restrict__ Qws, float* __restrict__ Kws)
{
    __shared__ float s_seq[GP_ROWS][SEQ_PAD];
    const int t = threadIdx.x;
    const int R0 = blockIdx.x * GP_ROWS;

    for (int idx = t; idx < GP_ROWS * EMB; idx += 256) {
        int r = idx / EMB, d = idx - r * EMB;
        int g = items[R0 + r];
        float v = 0.f;
        if (g > 0) {
            size_t o32 = (size_t)(g - 1) * EMB + d;
            size_t obf = (size_t)(g - 1) * EMBP + d;
            v = (emb0[o32] + bf2f(e1b[obf]) + bf2f(e2b[obf])) * (1.f / 3.f);
        }
        s_seq[r][d] = v;
        seqws[(size_t)(R0 + r) * EMB + d] = v;
    }
    __syncthreads();

    if (t >= 224) return;
    const int rg = t / 28;
    const int e0 = (t % 28) * 4;

    float accq[4][4] = {{0.f}}, acck[4][4] = {{0.f}};
    for (int d4 = 0; d4 < 28; ++d4) {
        float sa[4][4];
        #pragma unroll
        for (int rr = 0; rr < 4; ++rr) {
            float4 v = *(const float4*)&s_seq[rg * 4 + rr][d4 * 4];
            sa[rr][0] = v.x; sa[rr][1] = v.y; sa[rr][2] = v.z; sa[rr][3] = v.w;
        }
        #pragma unroll
        for (int j = 0; j < 4; ++j) {
            const int d = d4 * 4 + j;
            float4 wq = *(const float4*)&Wq[d * EMB + e0];
            float4 wk = *(const float4*)&Wk[d * EMB + e0];
            #pragma unroll
            for (int rr = 0; rr < 4; ++rr) {
                float s = sa[rr][j];
                accq[rr][0] += s * wq.x; accq[rr][1] += s * wq.y;
                accq[rr][2] += s * wq.z; accq[rr][3] += s * wq.w;
                acck[rr][0] += s * wk.x; acck[rr][1] += s * wk.y;
                acck[rr][2] += s * wk.z; acck[rr][3] += s * wk.w;
            }
        }
    }
    #pragma unroll
    for (int rr = 0; rr < 4; ++rr) {
        size_t o = (size_t)(R0 + rg * 4 + rr) * EMB + e0;
        float4 q, k;
        q.x = 1.f / (1.f + __expf(-accq[rr][0]));
        q.y = 1.f / (1.f + __expf(-accq[rr][1]));
        q.z = 1.f / (1.f + __expf(-accq[rr][2]));
        q.w = 1.f / (1.f + __expf(-accq[rr][3]));
        k.x = 1.f / (1.f + __expf(-acck[rr][0]));
        k.y = 1.f / (1.f + __expf(-acck[rr][1]));
        k.z = 1.f / (1.f + __expf(-acck[rr][2]));
        k.w = 1.f / (1.f + __expf(-acck[rr][3]));
        *(float4*)&Qws[o] = q;
        *(float4*)&Kws[o] = k;
    }
}

// ---------------- scores + softmax + pooling (no LDS atomics) --------------
__global__ __launch_bounds__(256) void attn_score_pool(
    const float* __restrict__ Qws, const float* __restrict__ Kws,
    const float* __restrict__ seqws,
    const int* __restrict__ session_len, const float* __restrict__ mask,
    float* __restrict__ seq_h, float* __restrict__ acc2)
{
    __shared__ float sQ[SEQL][SEQ_PAD];
    __shared__ float sK[SEQL][SEQ_PAD];
    __shared__ float s_part[SEQL][4];
    __shared__ float s_mask[SEQL];
    __shared__ float s_beta[SEQL];

    const int b = blockIdx.x;
    const int t = threadIdx.x;

    for (int idx = t; idx < SEQL * (EMB / 4); idx += 256) {
        int l = idx / (EMB / 4), d4 = idx - l * (EMB / 4);
        *(float4*)&sQ[l][d4 * 4] = *(const float4*)&Qws[((size_t)b * SEQL + l) * EMB + d4 * 4];
        *(float4*)&sK[l][d4 * 4] = *(const float4*)&Kws[((size_t)b * SEQL + l) * EMB + d4 * 4];
    }
    if (t < SEQL) s_mask[t] = mask[b * SEQL + t];
    __syncthreads();

    const float inv_sqrt_d = rsqrtf((float)EMB);
    if (t < 200) {
        const int l = t >> 2;
        const int m0 = t & 3;
        float partial = 0.f;
        if (s_mask[l] != 0.f) {
            for (int m = m0; m < SEQL; m += 4) {
                if (m == l || s_mask[m] == 0.f) continue;
                float dot = 0.f;
                for (int d4 = 0; d4 < EMB / 4; ++d4) {
                    float4 a = *(const float4*)&sQ[l][d4 * 4];
                    float4 c = *(const float4*)&sK[m][d4 * 4];
                    dot += a.x * c.x + a.y * c.y + a.z * c.z + a.w * c.w;
                }
                partial += inv_sqrt_d / (1.f + __expf(-dot));
            }
        }
        s_part[l][m0] = partial;
    }
    __syncthreads();

    if (t < 64) {
        float slen = (float)session_len[b];
        float a = -1e30f;
        if (t < SEQL && s_mask[t] > 0.f)
            a = (s_part[t][0] + s_part[t][1] + s_part[t][2] + s_part[t][3]) / slen;
        float mx = a;
        for (int o = 32; o > 0; o >>= 1) mx = fmaxf(mx, __shfl_xor(mx, o));
        float ex = __expf(a - mx);
        float sm = ex;
        for (int o = 32; o > 0; o >>= 1) sm += __shfl_xor(sm, o);
        if (t < SEQL) s_beta[t] = ex / sm;
    }
    __syncthreads();

    if (t < EMB) {
        float h = 0.f;
        for (int l = 0; l < SEQL; ++l)
            h += s_beta[l] * seqws[((size_t)b * SEQL + l) * EMB + t];
        seq_h[b * EMB + t] = h;
        acc2[b * EMB + t] = h;
    }
}

// ---------------- DA = D @ A  (32x32 LDS-tiled) ----------------------------
__global__ __launch_bounds__(256) void gemm_DA(
    const float* __restrict__ D, const float* __restrict__ A,
    float* __restrict__ DA)
{
    __shared__ float sD[32][33];
    __shared__ float sA[32][33];
    const int tx = threadIdx.x & 15;
    const int ty = threadIdx.x >> 4;
    const int i0 = blockIdx.y * 32;
    const int j0 = blockIdx.x * 32;
    float a00 = 0.f, a01 = 0.f, a10 = 0.f, a11 = 0.f;
    for (int k0 = 0; k0 < BATCH; k0 += 32) {
        for (int idx = threadIdx.x; idx < 1024; idx += 256) {
            int r = idx >> 5, c = idx & 31;
            sD[r][c] = D[(i0 + r) * BATCH + k0 + c];
            sA[r][c] = A[(k0 + r) * BATCH + j0 + c];
        }
        __syncthreads();
        #pragma unroll 8
        for (int kk = 0; kk < 32; ++kk) {
            float d0 = sD[2 * ty][kk], d1 = sD[2 * ty + 1][kk];
            float b0 = sA[kk][2 * tx], b1 = sA[kk][2 * tx + 1];
            a00 += d0 * b0; a01 += d0 * b1;
            a10 += d1 * b0; a11 += d1 * b1;
        }
        __syncthreads();
    }
    DA[(i0 + 2 * ty) * BATCH + j0 + 2 * tx] = a00;
    DA[(i0 + 2 * ty) * BATCH + j0 + 2 * tx + 1] = a01;
    DA[(i0 + 2 * ty + 1) * BATCH + j0 + 2 * tx] = a10;
    DA[(i0 + 2 * ty + 1) * BATCH + j0 + 2 * tx + 1] = a11;
}

// ---------------- t = s @ W^T ----------------------------------------------
__global__ __launch_bounds__(128) void sess_linear(
    const float* __restrict__ s, const float* __restrict__ W,
    float* __restrict__ t)
{
    __shared__ float s_row[EMB];
    int b = blockIdx.x;
    int e = threadIdx.x;
    if (e < EMB) s_row[e] = s[b * EMB + e];
    __syncthreads();
    if (e >= EMB) return;
    float acc = 0.f;
    for (int d = 0; d < EMB; ++d) acc += s_row[d] * W[e * EMB + d];
    t[b * EMB + e] = acc;
}

// ---------------- s = DA @ t; acc2 += s/||s||; last: out = acc2/3 ----------
__global__ __launch_bounds__(128) void sess_prop(
    const float* __restrict__ DA, const float* __restrict__ t,
    float* __restrict__ s_out, float* __restrict__ acc2,
    float* __restrict__ out, int is_last)
{
    __shared__ float s_da[BATCH];
    __shared__ float s_sq[128];
    int b = blockIdx.x;
    int e = threadIdx.x;
    for (int k = e; k < BATCH; k += 128) s_da[k] = DA[b * BATCH + k];
    __syncthreads();

    float v = 0.f;
    if (e < EMB) {
        for (int k = 0; k < BATCH; ++k) v += s_da[k] * t[k * EMB + e];
    }
    s_sq[e] = (e < EMB) ? v * v : 0.f;
    __syncthreads();
    for (int off = 64; off > 0; off >>= 1) {
        if (e < off) s_sq[e] += s_sq[e + off];
        __syncthreads();
    }
    float nrm = fmaxf(sqrtf(s_sq[0]), 1e-12f);
    if (e < EMB) {
        float a = acc2[b * EMB + e] + v / nrm;
        acc2[b * EMB + e] = a;
        s_out[b * EMB + e] = v;
        if (is_last) out[b * EMB + e] = a * (1.f / 3.f);
    }
}

extern "C" void kernel_launch(void* const* d_in, const int* in_sizes, int n_in,
                              void* d_out, int out_size, void* d_ws, size_t ws_size,
                              hipStream_t stream)
{
    (void)in_sizes; (void)n_in; (void)out_size; (void)ws_size;

    const float* embedding    = (const float*)d_in[0];
    const float* adj_vals     = (const float*)d_in[1];
    const float* W_q          = (const float*)d_in[2];
    const float* W_k          = (const float*)d_in[3];
    const float* w_sess       = (const float*)d_in[4];
    const float* D            = (const float*)d_in[5];
    const float* A            = (const float*)d_in[6];
    const int*   adj_rows     = (const int*)d_in[7];
    const int*   adj_cols     = (const int*)d_in[8];
    const int*   session_item = (const int*)d_in[9];
    const int*   session_len  = (const int*)d_in[10];
    const float* mask         = (const float*)d_in[11];
    float* out = (float*)d_out;

    // ---- workspace layout ----
    unsigned short* ebf0 = (unsigned short*)d_ws;                 // 3 x 12.8M ushort (padded)
    unsigned short* ebf1 = ebf0 + (size_t)N_NODE * EMBP;
    unsigned short* ebf2 = ebf1 + (size_t)N_NODE * EMBP;
    float* DAb       = (float*)(ebf2 + (size_t)N_NODE * EMBP);    // 8B-aligned
    float* seqh      = DAb  + (size_t)BATCH * BATCH;
    float* acc2      = seqh + (size_t)BATCH * EMB;
    float* tbuf      = acc2 + (size_t)BATCH * EMB;
    float* sbuf      = tbuf + (size_t)BATCH * EMB;
    float* seqws     = sbuf + (size_t)BATCH * EMB;                // 34.4 MB region
    float* Qws       = seqws + (size_t)NROWS * EMB;
    float* Kws       = Qws   + (size_t)NROWS * EMB;
    int*   counts    = (int*)(Kws + (size_t)NROWS * EMB);
    int*   row_start = counts + N_NODE;
    int*   needed    = row_start + N_NODE;                        // needed+bcur adjacent
    int*   bcur      = needed + N_NODE;                           // NBUCK, pad 2048
    int2*  csr_cv    = (int2*)(bcur + 2048);                      // NBUCK*BUCK_CAP = 19.2 MB
    // staged aliases seqws/Qws/Kws (dead before gather_project writes them)
    uint2* staged    = (uint2*)seqws;                             // 19.2 MB < 34.4 MB

    // one memset covers needed + bcur (adjacent)
    hipMemsetAsync(needed, 0, (N_NODE + 2048) * sizeof(int), stream);

    // ---- prep: padded bf16 table + mark_needed (fused) ----
    prep<<<N_NODE * 32 / 256, 256, 0, stream>>>(embedding, ebf0,
                                                session_item, needed);

    // ---- build CSR: two-phase block-aggregated bucket build ----
    edge_bin<<<P1_BLOCKS, 1024, 0, stream>>>(adj_rows, adj_cols, adj_vals,
                                             bcur, staged);
    bucket_build<<<NBUCK, 256, 0, stream>>>(staged, bcur, csr_cv,
                                            row_start, counts);

    // ---- hyperconv: layer1 all rows, layer2 only rows attention reads ----
    const int spmm_grid = N_NODE / 8;   // 12500, exact
    spmm_bf16<<<spmm_grid, 256, 0, stream>>>(ebf0, csr_cv, row_start, counts,
                                             needed, 0, ebf1);
    spmm_bf16<<<spmm_grid, 256, 0, stream>>>(ebf1, csr_cv, row_start, counts,
                                             needed, 1, ebf2);

    // ---- attention ----
    gather_project<<<NROWS / GP_ROWS, 256, 0, stream>>>(embedding, ebf1, ebf2,
                                                        session_item, W_q, W_k,
                                                        seqws, Qws, Kws);
    attn_score_pool<<<BATCH, 256, 0, stream>>>(Qws, Kws, seqws, session_len, mask,
                                               seqh, acc2);

    // ---- session graph ----
    gemm_DA<<<dim3(16, 16), 256, 0, stream>>>(D, A, DAb);
    sess_linear<<<BATCH, 128, 0, stream>>>(seqh, w_sess + 0 * EMB * EMB, tbuf);
    sess_prop  <<<BATCH, 128, 0, stream>>>(DAb, tbuf, sbuf, acc2, out, 0);
    sess_linear<<<BATCH, 128, 0, stream>>>(sbuf, w_sess + 1 * EMB * EMB, tbuf);
    sess_prop  <<<BATCH, 128, 0, stream>>>(DAb, tbuf, sbuf, acc2, out, 1);
}

// Round 10
// 388.867 us; speedup vs baseline: 1.1164x; 1.1164x over previous
//
#include <hip/hip_runtime.h>

#define N_NODE 100000
#define EMB 112
#define EMBP 128                      // padded bf16 row: 256 B, line-aligned
#define BATCH 512
#define SEQL 50
#define NNZ 1600000
#define NROWS (BATCH * SEQL)          // 25600 flattened session slots

#define BROWS 256                     // rows per bucket
#define NBUCK ((N_NODE + BROWS - 1) / BROWS)      // 391
#define BUCK_CAP 4608                 // mean 4096, sd 64 -> 8 sigma headroom
#define TILE_E 6250                   // 256 blocks x 1024 threads, exact
#define P1_BLOCKS 256

__device__ __forceinline__ float bf2f(unsigned short u) {
    return __uint_as_float((unsigned)u << 16);
}
__device__ __forceinline__ unsigned short f2bf(float f) {
    unsigned u = __float_as_uint(f);
    return (unsigned short)((u + 0x7FFF + ((u >> 16) & 1)) >> 16);   // RNE
}

// ---------------- prep: fp32 -> padded bf16 table + mark_needed ------------
__global__ __launch_bounds__(256) void prep(
    const float* __restrict__ in, unsigned short* __restrict__ out,
    const int* __restrict__ items, int* __restrict__ needed)
{
    int i = blockIdx.x * 256 + threadIdx.x;
    int r = i >> 5, c = i & 31;
    ushort4 o; o.x = 0; o.y = 0; o.z = 0; o.w = 0;
    if (c < 28) {
        float4 v = ((const float4*)in)[r * 28 + c];
        o.x = f2bf(v.x); o.y = f2bf(v.y); o.z = f2bf(v.z); o.w = f2bf(v.w);
    }
    ((ushort4*)out)[i] = o;
    if (i < NROWS) {
        int g = items[i];
        if (g > 0) needed[g - 1] = 1;   // benign races, all write 1
    }
}

// ---- phase 1: block-aggregated binning into 256-row bucket regions --------
// 391 buckets -> per-(block,bucket) span ~16 edges = 128 B (low write amp).
__global__ __launch_bounds__(1024) void edge_bin(
    const int* __restrict__ rows, const int* __restrict__ cols,
    const float* __restrict__ vals,
    int* __restrict__ bcur, uint2* __restrict__ staged)
{
    __shared__ int hist[NBUCK];
    const int t = threadIdx.x;
    const int e0 = blockIdx.x * TILE_E;
    const int e1 = e0 + TILE_E;

    for (int i = t; i < NBUCK; i += 1024) hist[i] = 0;
    __syncthreads();
    for (int e = e0 + t; e < e1; e += 1024)
        atomicAdd(&hist[rows[e] >> 8], 1);
    __syncthreads();
    for (int i = t; i < NBUCK; i += 1024) {
        int c = hist[i];
        hist[i] = (c > 0) ? atomicAdd(&bcur[i], c) : 0;
    }
    __syncthreads();
    for (int e = e0 + t; e < e1; e += 1024) {
        int r = rows[e];
        int b = r >> 8;
        int k = atomicAdd(&hist[b], 1);
        uint2 s;
        s.x = ((unsigned)(r & 255) << 24) | (unsigned)cols[e];
        s.y = __float_as_uint(vals[e]);
        staged[(size_t)b * BUCK_CAP + k] = s;
    }
}

// ---- fused: bucket-local sort (LDS) + csr emit + spmm layer 1 -------------
// One block per bucket. Sorted edges live in LDS; spmm1 reads them via
// broadcast ds_read. Emits csr_cv/row_start/counts for spmm2.
__global__ __launch_bounds__(1024) void bucket_csr_spmm(
    const uint2* __restrict__ staged, const int* __restrict__ bcur,
    const unsigned short* __restrict__ src, unsigned short* __restrict__ dst,
    int2* __restrict__ csr_cv, int* __restrict__ row_start,
    int* __restrict__ counts)
{
    __shared__ uint2 s_sorted[BUCK_CAP];
    __shared__ int cnt[BROWS];
    __shared__ int sc[BROWS];     // inclusive scan (stays fixed after scan)
    __shared__ int cur[BROWS];    // mutable scatter cursor

    const int b = blockIdx.x;
    const int t = threadIdx.x;
    const int n = bcur[b];
    const size_t base = (size_t)b * BUCK_CAP;
    const int r0 = b << 8;

    // phase A: count
    if (t < BROWS) cnt[t] = 0;
    __syncthreads();
    for (int i = t; i < n; i += 1024)
        atomicAdd(&cnt[staged[base + i].x >> 24], 1);
    __syncthreads();

    // phase B: scan 256 counts (Hillis-Steele in LDS)
    if (t < BROWS) sc[t] = cnt[t];
    __syncthreads();
    for (int o = 1; o < BROWS; o <<= 1) {
        int v = 0;
        if (t < BROWS && t >= o) v = sc[t - o];
        __syncthreads();
        if (t < BROWS) sc[t] += v;
        __syncthreads();
    }
    if (t < BROWS) {
        int excl = sc[t] - cnt[t];
        cur[t] = excl;
        int row = r0 + t;
        if (row < N_NODE) {
            row_start[row] = (int)base + excl;
            counts[row] = cnt[t];
        }
    }
    __syncthreads();

    // phase C: scatter into sorted LDS order (staged re-read hits L2)
    for (int i = t; i < n; i += 1024) {
        uint2 s = staged[base + i];
        int rl = s.x >> 24;
        int k = atomicAdd(&cur[rl], 1);
        uint2 e;
        e.x = s.x & 0x00FFFFFFu;   // col
        e.y = s.y;                 // val bits
        s_sorted[k] = e;
    }
    __syncthreads();

    // phase D: stream csr_cv out (coalesced) for spmm layer 2
    for (int i = t; i < n; i += 1024) {
        uint2 e = s_sorted[i];
        int2 cv; cv.x = (int)e.x; cv.y = (int)e.y;
        csr_cv[base + i] = cv;
    }

    // phase E: spmm layer 1 for this bucket's 256 rows, edges from LDS
    const int wave = t >> 6;
    const int lane = t & 63;
    const int half = lane >> 5;
    const int hl = lane & 31;
    const int d0 = hl * 4;

    for (int it = 0; it < 8; ++it) {
        int rl = wave * 16 + it * 2 + half;
        int row = r0 + rl;
        bool valid = row < N_NODE;
        int n_r = valid ? cnt[rl] : 0;
        int beg = valid ? (sc[rl] - cnt[rl]) : 0;

        float a0 = 0.f, a1 = 0.f, a2 = 0.f, a3 = 0.f;
        int i = 0;
        for (; i + 8 <= n_r; i += 8) {
            #pragma unroll
            for (int j = 0; j < 8; ++j) {
                uint2 e = s_sorted[beg + i + j];
                float v = __uint_as_float(e.y);
                ushort4 u = *(const ushort4*)(src + (size_t)e.x * EMBP + d0);
                a0 += v * bf2f(u.x);
                a1 += v * bf2f(u.y);
                a2 += v * bf2f(u.z);
                a3 += v * bf2f(u.w);
            }
        }
        for (; i < n_r; ++i) {
            uint2 e = s_sorted[beg + i];
            float v = __uint_as_float(e.y);
            ushort4 u = *(const ushort4*)(src + (size_t)e.x * EMBP + d0);
            a0 += v * bf2f(u.x);
            a1 += v * bf2f(u.y);
            a2 += v * bf2f(u.z);
            a3 += v * bf2f(u.w);
        }
        if (valid) {
            ushort4 o;
            o.x = f2bf(a0); o.y = f2bf(a1); o.z = f2bf(a2); o.w = f2bf(a3);
            *(ushort4*)(dst + (size_t)row * EMBP + d0) = o;
        }
    }
}

// ---------------- HyperConv layer 2: padded bf16 gather, needed rows only --
__global__ __launch_bounds__(256) void spmm_bf16(
    const unsigned short* __restrict__ src, const int2* __restrict__ csr_cv,
    const int* __restrict__ row_start, const int* __restrict__ counts,
    const int* __restrict__ needed, unsigned short* __restrict__ dst)
{
    const int lane = threadIdx.x & 63;
    const int wave = threadIdx.x >> 6;
    const int half = lane >> 5;
    const int hl = lane & 31;
    const int row = blockIdx.x * 8 + wave * 2 + half;   // grid covers N_NODE
    const int d0 = hl * 4;

    const bool skip = (needed[row] == 0);
    int n = skip ? 0 : counts[row];
    const int beg = row_start[row];

    float a0 = 0.f, a1 = 0.f, a2 = 0.f, a3 = 0.f;
    int i = 0;
    for (; i + 8 <= n; i += 8) {
        #pragma unroll
        for (int j = 0; j < 8; ++j) {
            int2 cv = csr_cv[beg + i + j];
            float v = __int_as_float(cv.y);
            ushort4 u = *(const ushort4*)(src + (size_t)cv.x * EMBP + d0);
            a0 += v * bf2f(u.x);
            a1 += v * bf2f(u.y);
            a2 += v * bf2f(u.z);
            a3 += v * bf2f(u.w);
        }
    }
    for (; i < n; ++i) {
        int2 cv = csr_cv[beg + i];
        float v = __int_as_float(cv.y);
        ushort4 u = *(const ushort4*)(src + (size_t)cv.x * EMBP + d0);
        a0 += v * bf2f(u.x);
        a1 += v * bf2f(u.y);
        a2 += v * bf2f(u.z);
        a3 += v * bf2f(u.w);
    }
    if (!skip) {
        ushort4 o;
        o.x = f2bf(a0); o.y = f2bf(a1); o.z = f2bf(a2); o.w = f2bf(a3);
        *(ushort4*)(dst + (size_t)row * EMBP + d0) = o;
    }
}

// ---------------- gather + Q/K projection (register-tiled) -----------------
#define GP_ROWS 32
#define SEQ_PAD 116
__global__ __launch_bounds__(256) void gather_project(
    const float* __restrict__ emb0,
    const unsigned short* __restrict__ e1b, const unsigned short* __restrict__ e2b,
    const int* __restrict__ items,
    const float* __restrict__ Wq, const float* __restrict__ Wk,
    float* __restrict__ seqws, float* __restrict__ Qws, float* __restrict__ Kws)
{
    __shared__ float s_seq[GP_ROWS][SEQ_PAD];
    const int t = threadIdx.x;
    const int R0 = blockIdx.x * GP_ROWS;

    for (int idx = t; idx < GP_ROWS * EMB; idx += 256) {
        int r = idx / EMB, d = idx - r * EMB;
        int g = items[R0 + r];
        float v = 0.f;
        if (g > 0) {
            size_t o32 = (size_t)(g - 1) * EMB + d;
            size_t obf = (size_t)(g - 1) * EMBP + d;
            v = (emb0[o32] + bf2f(e1b[obf]) + bf2f(e2b[obf])) * (1.f / 3.f);
        }
        s_seq[r][d] = v;
        seqws[(size_t)(R0 + r) * EMB + d] = v;
    }
    __syncthreads();

    if (t >= 224) return;
    const int rg = t / 28;
    const int e0 = (t % 28) * 4;

    float accq[4][4] = {{0.f}}, acck[4][4] = {{0.f}};
    for (int d4 = 0; d4 < 28; ++d4) {
        float sa[4][4];
        #pragma unroll
        for (int rr = 0; rr < 4; ++rr) {
            float4 v = *(const float4*)&s_seq[rg * 4 + rr][d4 * 4];
            sa[rr][0] = v.x; sa[rr][1] = v.y; sa[rr][2] = v.z; sa[rr][3] = v.w;
        }
        #pragma unroll
        for (int j = 0; j < 4; ++j) {
            const int d = d4 * 4 + j;
            float4 wq = *(const float4*)&Wq[d * EMB + e0];
            float4 wk = *(const float4*)&Wk[d * EMB + e0];
            #pragma unroll
            for (int rr = 0; rr < 4; ++rr) {
                float s = sa[rr][j];
                accq[rr][0] += s * wq.x; accq[rr][1] += s * wq.y;
                accq[rr][2] += s * wq.z; accq[rr][3] += s * wq.w;
                acck[rr][0] += s * wk.x; acck[rr][1] += s * wk.y;
                acck[rr][2] += s * wk.z; acck[rr][3] += s * wk.w;
            }
        }
    }
    #pragma unroll
    for (int rr = 0; rr < 4; ++rr) {
        size_t o = (size_t)(R0 + rg * 4 + rr) * EMB + e0;
        float4 q, k;
        q.x = 1.f / (1.f + __expf(-accq[rr][0]));
        q.y = 1.f / (1.f + __expf(-accq[rr][1]));
        q.z = 1.f / (1.f + __expf(-accq[rr][2]));
        q.w = 1.f / (1.f + __expf(-accq[rr][3]));
        k.x = 1.f / (1.f + __expf(-acck[rr][0]));
        k.y = 1.f / (1.f + __expf(-acck[rr][1]));
        k.z = 1.f / (1.f + __expf(-acck[rr][2]));
        k.w = 1.f / (1.f + __expf(-acck[rr][3]));
        *(float4*)&Qws[o] = q;
        *(float4*)&Kws[o] = k;
    }
}

// ---------------- scores + softmax + pooling (no LDS atomics) --------------
__global__ __launch_bounds__(256) void attn_score_pool(
    const float* __restrict__ Qws, const float* __restrict__ Kws,
    const float* __restrict__ seqws,
    const int* __restrict__ session_len, const float* __restrict__ mask,
    float* __restrict__ seq_h, float* __restrict__ acc2)
{
    __shared__ float sQ[SEQL][SEQ_PAD];
    __shared__ float sK[SEQL][SEQ_PAD];
    __shared__ float s_part[SEQL][4];
    __shared__ float s_mask[SEQL];
    __shared__ float s_beta[SEQL];

    const int b = blockIdx.x;
    const int t = threadIdx.x;

    for (int idx = t; idx < SEQL * (EMB / 4); idx += 256) {
        int l = idx / (EMB / 4), d4 = idx - l * (EMB / 4);
        *(float4*)&sQ[l][d4 * 4] = *(const float4*)&Qws[((size_t)b * SEQL + l) * EMB + d4 * 4];
        *(float4*)&sK[l][d4 * 4] = *(const float4*)&Kws[((size_t)b * SEQL + l) * EMB + d4 * 4];
    }
    if (t < SEQL) s_mask[t] = mask[b * SEQL + t];
    __syncthreads();

    const float inv_sqrt_d = rsqrtf((float)EMB);
    if (t < 200) {
        const int l = t >> 2;
        const int m0 = t & 3;
        float partial = 0.f;
        if (s_mask[l] != 0.f) {
            for (int m = m0; m < SEQL; m += 4) {
                if (m == l || s_mask[m] == 0.f) continue;
                float dot = 0.f;
                for (int d4 = 0; d4 < EMB / 4; ++d4) {
                    float4 a = *(const float4*)&sQ[l][d4 * 4];
                    float4 c = *(const float4*)&sK[m][d4 * 4];
                    dot += a.x * c.x + a.y * c.y + a.z * c.z + a.w * c.w;
                }
                partial += inv_sqrt_d / (1.f + __expf(-dot));
            }
        }
        s_part[l][m0] = partial;
    }
    __syncthreads();

    if (t < 64) {
        float slen = (float)session_len[b];
        float a = -1e30f;
        if (t < SEQL && s_mask[t] > 0.f)
            a = (s_part[t][0] + s_part[t][1] + s_part[t][2] + s_part[t][3]) / slen;
        float mx = a;
        for (int o = 32; o > 0; o >>= 1) mx = fmaxf(mx, __shfl_xor(mx, o));
        float ex = __expf(a - mx);
        float sm = ex;
        for (int o = 32; o > 0; o >>= 1) sm += __shfl_xor(sm, o);
        if (t < SEQL) s_beta[t] = ex / sm;
    }
    __syncthreads();

    if (t < EMB) {
        float h = 0.f;
        for (int l = 0; l < SEQL; ++l)
            h += s_beta[l] * seqws[((size_t)b * SEQL + l) * EMB + t];
        seq_h[b * EMB + t] = h;
        acc2[b * EMB + t] = h;
    }
}

// ---------------- DA = D @ A  (32x32 LDS-tiled) ----------------------------
__global__ __launch_bounds__(256) void gemm_DA(
    const float* __restrict__ D, const float* __restrict__ A,
    float* __restrict__ DA)
{
    __shared__ float sD[32][33];
    __shared__ float sA[32][33];
    const int tx = threadIdx.x & 15;
    const int ty = threadIdx.x >> 4;
    const int i0 = blockIdx.y * 32;
    const int j0 = blockIdx.x * 32;
    float a00 = 0.f, a01 = 0.f, a10 = 0.f, a11 = 0.f;
    for (int k0 = 0; k0 < BATCH; k0 += 32) {
        for (int idx = threadIdx.x; idx < 1024; idx += 256) {
            int r = idx >> 5, c = idx & 31;
            sD[r][c] = D[(i0 + r) * BATCH + k0 + c];
            sA[r][c] = A[(k0 + r) * BATCH + j0 + c];
        }
        __syncthreads();
        #pragma unroll 8
        for (int kk = 0; kk < 32; ++kk) {
            float d0 = sD[2 * ty][kk], d1 = sD[2 * ty + 1][kk];
            float b0 = sA[kk][2 * tx], b1 = sA[kk][2 * tx + 1];
            a00 += d0 * b0; a01 += d0 * b1;
            a10 += d1 * b0; a11 += d1 * b1;
        }
        __syncthreads();
    }
    DA[(i0 + 2 * ty) * BATCH + j0 + 2 * tx] = a00;
    DA[(i0 + 2 * ty) * BATCH + j0 + 2 * tx + 1] = a01;
    DA[(i0 + 2 * ty + 1) * BATCH + j0 + 2 * tx] = a10;
    DA[(i0 + 2 * ty + 1) * BATCH + j0 + 2 * tx + 1] = a11;
}

// ---------------- t = s @ W^T ----------------------------------------------
__global__ __launch_bounds__(128) void sess_linear(
    const float* __restrict__ s, const float* __restrict__ W,
    float* __restrict__ t)
{
    __shared__ float s_row[EMB];
    int b = blockIdx.x;
    int e = threadIdx.x;
    if (e < EMB) s_row[e] = s[b * EMB + e];
    __syncthreads();
    if (e >= EMB) return;
    float acc = 0.f;
    for (int d = 0; d < EMB; ++d) acc += s_row[d] * W[e * EMB + d];
    t[b * EMB + e] = acc;
}

// ---------------- s = DA @ t; acc2 += s/||s||; last: out = acc2/3 ----------
__global__ __launch_bounds__(128) void sess_prop(
    const float* __restrict__ DA, const float* __restrict__ t,
    float* __restrict__ s_out, float* __restrict__ acc2,
    float* __restrict__ out, int is_last)
{
    __shared__ float s_da[BATCH];
    __shared__ float s_sq[128];
    int b = blockIdx.x;
    int e = threadIdx.x;
    for (int k = e; k < BATCH; k += 128) s_da[k] = DA[b * BATCH + k];
    __syncthreads();

    float v = 0.f;
    if (e < EMB) {
        for (int k = 0; k < BATCH; ++k) v += s_da[k] * t[k * EMB + e];
    }
    s_sq[e] = (e < EMB) ? v * v : 0.f;
    __syncthreads();
    for (int off = 64; off > 0; off >>= 1) {
        if (e < off) s_sq[e] += s_sq[e + off];
        __syncthreads();
    }
    float nrm = fmaxf(sqrtf(s_sq[0]), 1e-12f);
    if (e < EMB) {
        float a = acc2[b * EMB + e] + v / nrm;
        acc2[b * EMB + e] = a;
        s_out[b * EMB + e] = v;
        if (is_last) out[b * EMB + e] = a * (1.f / 3.f);
    }
}

extern "C" void kernel_launch(void* const* d_in, const int* in_sizes, int n_in,
                              void* d_out, int out_size, void* d_ws, size_t ws_size,
                              hipStream_t stream)
{
    (void)in_sizes; (void)n_in; (void)out_size; (void)ws_size;

    const float* embedding    = (const float*)d_in[0];
    const float* adj_vals     = (const float*)d_in[1];
    const float* W_q          = (const float*)d_in[2];
    const float* W_k          = (const float*)d_in[3];
    const float* w_sess       = (const float*)d_in[4];
    const float* D            = (const float*)d_in[5];
    const float* A            = (const float*)d_in[6];
    const int*   adj_rows     = (const int*)d_in[7];
    const int*   adj_cols     = (const int*)d_in[8];
    const int*   session_item = (const int*)d_in[9];
    const int*   session_len  = (const int*)d_in[10];
    const float* mask         = (const float*)d_in[11];
    float* out = (float*)d_out;

    // ---- workspace layout ----
    unsigned short* ebf0 = (unsigned short*)d_ws;                 // 3 x 12.8M ushort (padded)
    unsigned short* ebf1 = ebf0 + (size_t)N_NODE * EMBP;
    unsigned short* ebf2 = ebf1 + (size_t)N_NODE * EMBP;
    float* DAb       = (float*)(ebf2 + (size_t)N_NODE * EMBP);    // 8B-aligned
    float* seqh      = DAb  + (size_t)BATCH * BATCH;
    float* acc2      = seqh + (size_t)BATCH * EMB;
    float* tbuf      = acc2 + (size_t)BATCH * EMB;
    float* sbuf      = tbuf + (size_t)BATCH * EMB;
    float* seqws     = sbuf + (size_t)BATCH * EMB;                // 34.4 MB region
    float* Qws       = seqws + (size_t)NROWS * EMB;
    float* Kws       = Qws   + (size_t)NROWS * EMB;
    int*   counts    = (int*)(Kws + (size_t)NROWS * EMB);
    int*   row_start = counts + N_NODE;
    int*   needed    = row_start + N_NODE;                        // needed+bcur adjacent
    int*   bcur      = needed + N_NODE;                           // NBUCK, pad 2048
    int2*  csr_cv    = (int2*)(bcur + 2048);                      // NBUCK*BUCK_CAP = 14.4 MB
    // staged aliases seqws/Qws/Kws (dead before gather_project writes them)
    uint2* staged    = (uint2*)seqws;                             // 14.4 MB < 34.4 MB

    // one memset covers needed + bcur (adjacent)
    hipMemsetAsync(needed, 0, (N_NODE + 2048) * sizeof(int), stream);

    // ---- prep: padded bf16 table + mark_needed (fused) ----
    prep<<<N_NODE * 32 / 256, 256, 0, stream>>>(embedding, ebf0,
                                                session_item, needed);

    // ---- CSR build phase 1: bin edges into 256-row buckets ----
    edge_bin<<<P1_BLOCKS, 1024, 0, stream>>>(adj_rows, adj_cols, adj_vals,
                                             bcur, staged);

    // ---- fused: per-bucket sort + csr emit + hyperconv layer 1 ----
    bucket_csr_spmm<<<NBUCK, 1024, 0, stream>>>(staged, bcur, ebf0, ebf1,
                                                csr_cv, row_start, counts);

    // ---- hyperconv layer 2: only rows attention reads ----
    spmm_bf16<<<N_NODE / 8, 256, 0, stream>>>(ebf1, csr_cv, row_start, counts,
                                              needed, ebf2);

    // ---- attention ----
    gather_project<<<NROWS / GP_ROWS, 256, 0, stream>>>(embedding, ebf1, ebf2,
                                                        session_item, W_q, W_k,
                                                        seqws, Qws, Kws);
    attn_score_pool<<<BATCH, 256, 0, stream>>>(Qws, Kws, seqws, session_len, mask,
                                               seqh, acc2);

    // ---- session graph ----
    gemm_DA<<<dim3(16, 16), 256, 0, stream>>>(D, A, DAb);
    sess_linear<<<BATCH, 128, 0, stream>>>(seqh, w_sess + 0 * EMB * EMB, tbuf);
    sess_prop  <<<BATCH, 128, 0, stream>>>(DAb, tbuf, sbuf, acc2, out, 0);
    sess_linear<<<BATCH, 128, 0, stream>>>(sbuf, w_sess + 1 * EMB * EMB, tbuf);
    sess_prop  <<<BATCH, 128, 0, stream>>>(DAb, tbuf, sbuf, acc2, out, 1);
}

// Round 11
// 384.411 us; speedup vs baseline: 1.1293x; 1.0116x over previous
//
#include <hip/hip_runtime.h>

#define N_NODE 100000
#define EMB 112
#define EMBP 128                      // padded bf16 row: 256 B, line-aligned
#define BATCH 512
#define SEQL 50
#define NNZ 1600000
#define NROWS (BATCH * SEQL)          // 25600 flattened session slots

#define BROWS 256                     // rows per bucket
#define NBUCK ((N_NODE + BROWS - 1) / BROWS)      // 391
#define BUCK_CAP 4608                 // mean 4096, sd 64 -> 8 sigma headroom
#define TILE_E 6250                   // 256 blocks x 1024 threads, exact
#define P1_BLOCKS 256

__device__ __forceinline__ float bf2f(unsigned short u) {
    return __uint_as_float((unsigned)u << 16);
}
__device__ __forceinline__ unsigned short f2bf(float f) {
    unsigned u = __float_as_uint(f);
    return (unsigned short)((u + 0x7FFF + ((u >> 16) & 1)) >> 16);   // RNE
}

// ---------------- prep: fp32 -> padded bf16 table + mark_needed ------------
__global__ __launch_bounds__(256) void prep(
    const float* __restrict__ in, unsigned short* __restrict__ out,
    const int* __restrict__ items, int* __restrict__ needed)
{
    int i = blockIdx.x * 256 + threadIdx.x;
    int r = i >> 5, c = i & 31;
    ushort4 o; o.x = 0; o.y = 0; o.z = 0; o.w = 0;
    if (c < 28) {
        float4 v = ((const float4*)in)[r * 28 + c];
        o.x = f2bf(v.x); o.y = f2bf(v.y); o.z = f2bf(v.z); o.w = f2bf(v.w);
    }
    ((ushort4*)out)[i] = o;
    if (i < NROWS) {
        int g = items[i];
        if (g > 0) needed[g - 1] = 1;   // benign races, all write 1
    }
}

// ---- phase 1: block-aggregated binning into 256-row bucket regions --------
__global__ __launch_bounds__(1024) void edge_bin(
    const int* __restrict__ rows, const int* __restrict__ cols,
    const float* __restrict__ vals,
    int* __restrict__ bcur, uint2* __restrict__ staged)
{
    __shared__ int hist[NBUCK];
    const int t = threadIdx.x;
    const int e0 = blockIdx.x * TILE_E;
    const int e1 = e0 + TILE_E;

    for (int i = t; i < NBUCK; i += 1024) hist[i] = 0;
    __syncthreads();
    for (int e = e0 + t; e < e1; e += 1024)
        atomicAdd(&hist[rows[e] >> 8], 1);
    __syncthreads();
    for (int i = t; i < NBUCK; i += 1024) {
        int c = hist[i];
        hist[i] = (c > 0) ? atomicAdd(&bcur[i], c) : 0;
    }
    __syncthreads();
    for (int e = e0 + t; e < e1; e += 1024) {
        int r = rows[e];
        int b = r >> 8;
        int k = atomicAdd(&hist[b], 1);
        uint2 s;
        s.x = ((unsigned)(r & 255) << 24) | (unsigned)cols[e];
        s.y = __float_as_uint(vals[e]);
        staged[(size_t)b * BUCK_CAP + k] = s;
    }
}

// ---- fused: bucket-local sort (LDS) + csr emit + spmm layer 1 -------------
__global__ __launch_bounds__(1024) void bucket_csr_spmm(
    const uint2* __restrict__ staged, const int* __restrict__ bcur,
    const unsigned short* __restrict__ src, unsigned short* __restrict__ dst,
    int2* __restrict__ csr_cv, int* __restrict__ row_start,
    int* __restrict__ counts)
{
    __shared__ uint2 s_sorted[BUCK_CAP];
    __shared__ int cnt[BROWS];
    __shared__ int sc[BROWS];     // inclusive scan (stays fixed after scan)
    __shared__ int cur[BROWS];    // mutable scatter cursor

    const int b = blockIdx.x;
    const int t = threadIdx.x;
    const int n = bcur[b];
    const size_t base = (size_t)b * BUCK_CAP;
    const int r0 = b << 8;

    // phase A: count
    if (t < BROWS) cnt[t] = 0;
    __syncthreads();
    for (int i = t; i < n; i += 1024)
        atomicAdd(&cnt[staged[base + i].x >> 24], 1);
    __syncthreads();

    // phase B: scan 256 counts (Hillis-Steele in LDS)
    if (t < BROWS) sc[t] = cnt[t];
    __syncthreads();
    for (int o = 1; o < BROWS; o <<= 1) {
        int v = 0;
        if (t < BROWS && t >= o) v = sc[t - o];
        __syncthreads();
        if (t < BROWS) sc[t] += v;
        __syncthreads();
    }
    if (t < BROWS) {
        int excl = sc[t] - cnt[t];
        cur[t] = excl;
        int row = r0 + t;
        if (row < N_NODE) {
            row_start[row] = (int)base + excl;
            counts[row] = cnt[t];
        }
    }
    __syncthreads();

    // phase C: scatter into sorted LDS order (staged re-read hits L2)
    for (int i = t; i < n; i += 1024) {
        uint2 s = staged[base + i];
        int rl = s.x >> 24;
        int k = atomicAdd(&cur[rl], 1);
        uint2 e;
        e.x = s.x & 0x00FFFFFFu;   // col
        e.y = s.y;                 // val bits
        s_sorted[k] = e;
    }
    __syncthreads();

    // phase D: stream csr_cv out (coalesced) for spmm layer 2
    for (int i = t; i < n; i += 1024) {
        uint2 e = s_sorted[i];
        int2 cv; cv.x = (int)e.x; cv.y = (int)e.y;
        csr_cv[base + i] = cv;
    }

    // phase E: spmm layer 1 for this bucket's 256 rows, edges from LDS
    const int wave = t >> 6;
    const int lane = t & 63;
    const int half = lane >> 5;
    const int hl = lane & 31;
    const int d0 = hl * 4;

    for (int it = 0; it < 8; ++it) {
        int rl = wave * 16 + it * 2 + half;
        int row = r0 + rl;
        bool valid = row < N_NODE;
        int n_r = valid ? cnt[rl] : 0;
        int beg = valid ? (sc[rl] - cnt[rl]) : 0;

        float a0 = 0.f, a1 = 0.f, a2 = 0.f, a3 = 0.f;
        int i = 0;
        for (; i + 8 <= n_r; i += 8) {
            #pragma unroll
            for (int j = 0; j < 8; ++j) {
                uint2 e = s_sorted[beg + i + j];
                float v = __uint_as_float(e.y);
                ushort4 u = *(const ushort4*)(src + (size_t)e.x * EMBP + d0);
                a0 += v * bf2f(u.x);
                a1 += v * bf2f(u.y);
                a2 += v * bf2f(u.z);
                a3 += v * bf2f(u.w);
            }
        }
        for (; i < n_r; ++i) {
            uint2 e = s_sorted[beg + i];
            float v = __uint_as_float(e.y);
            ushort4 u = *(const ushort4*)(src + (size_t)e.x * EMBP + d0);
            a0 += v * bf2f(u.x);
            a1 += v * bf2f(u.y);
            a2 += v * bf2f(u.z);
            a3 += v * bf2f(u.w);
        }
        if (valid) {
            ushort4 o;
            o.x = f2bf(a0); o.y = f2bf(a1); o.z = f2bf(a2); o.w = f2bf(a3);
            *(ushort4*)(dst + (size_t)row * EMBP + d0) = o;
        }
    }
}

// ---------------- HyperConv layer 2: padded bf16 gather, needed rows only --
__global__ __launch_bounds__(256) void spmm_bf16(
    const unsigned short* __restrict__ src, const int2* __restrict__ csr_cv,
    const int* __restrict__ row_start, const int* __restrict__ counts,
    const int* __restrict__ needed, unsigned short* __restrict__ dst)
{
    const int lane = threadIdx.x & 63;
    const int wave = threadIdx.x >> 6;
    const int half = lane >> 5;
    const int hl = lane & 31;
    const int row = blockIdx.x * 8 + wave * 2 + half;   // grid covers N_NODE
    const int d0 = hl * 4;

    const bool skip = (needed[row] == 0);
    int n = skip ? 0 : counts[row];
    const int beg = row_start[row];

    float a0 = 0.f, a1 = 0.f, a2 = 0.f, a3 = 0.f;
    int i = 0;
    for (; i + 8 <= n; i += 8) {
        #pragma unroll
        for (int j = 0; j < 8; ++j) {
            int2 cv = csr_cv[beg + i + j];
            float v = __int_as_float(cv.y);
            ushort4 u = *(const ushort4*)(src + (size_t)cv.x * EMBP + d0);
            a0 += v * bf2f(u.x);
            a1 += v * bf2f(u.y);
            a2 += v * bf2f(u.z);
            a3 += v * bf2f(u.w);
        }
    }
    for (; i < n; ++i) {
        int2 cv = csr_cv[beg + i];
        float v = __int_as_float(cv.y);
        ushort4 u = *(const ushort4*)(src + (size_t)cv.x * EMBP + d0);
        a0 += v * bf2f(u.x);
        a1 += v * bf2f(u.y);
        a2 += v * bf2f(u.z);
        a3 += v * bf2f(u.w);
    }
    if (!skip) {
        ushort4 o;
        o.x = f2bf(a0); o.y = f2bf(a1); o.z = f2bf(a2); o.w = f2bf(a3);
        *(ushort4*)(dst + (size_t)row * EMBP + d0) = o;
    }
}

// ---------------- fused attention: gather + Q/K proj + scores + pool -------
// One block per batch element. Everything LDS-resident; no global intermediates.
#define APAD 116
__global__ __launch_bounds__(256) void attn_fused(
    const float* __restrict__ emb0,
    const unsigned short* __restrict__ e1b, const unsigned short* __restrict__ e2b,
    const int* __restrict__ items,
    const float* __restrict__ Wq, const float* __restrict__ Wk,
    const int* __restrict__ session_len, const float* __restrict__ mask,
    float* __restrict__ seq_h, float* __restrict__ acc2)
{
    __shared__ float s_seq[52][APAD];      // rows 50,51 are zero pad
    __shared__ float sQ[SEQL][APAD];
    __shared__ float sK[SEQL][APAD];
    __shared__ float s_part[SEQL][4];
    __shared__ float s_mask[SEQL];
    __shared__ float s_beta[SEQL];

    const int b = blockIdx.x;
    const int t = threadIdx.x;

    // gather 52 rows (last 2 forced zero)
    for (int idx = t; idx < 52 * EMB; idx += 256) {
        int r = idx / EMB, d = idx - r * EMB;
        int g = (r < SEQL) ? items[b * SEQL + r] : 0;
        float v = 0.f;
        if (g > 0) {
            size_t o32 = (size_t)(g - 1) * EMB + d;
            size_t obf = (size_t)(g - 1) * EMBP + d;
            v = (emb0[o32] + bf2f(e1b[obf]) + bf2f(e2b[obf])) * (1.f / 3.f);
        }
        s_seq[r][d] = v;
    }
    if (t < SEQL) s_mask[t] = mask[b * SEQL + t];
    __syncthreads();

    // Q/K projection: 4-row x 4-col register tiles; 13 row groups x 28 col quads
    for (int u = t; u < 13 * 28; u += 256) {
        const int rg = u / 28;
        const int e0 = (u - rg * 28) * 4;
        float accq[4][4] = {{0.f}}, acck[4][4] = {{0.f}};
        for (int d4 = 0; d4 < 28; ++d4) {
            float sa[4][4];
            #pragma unroll
            for (int rr = 0; rr < 4; ++rr) {
                float4 v = *(const float4*)&s_seq[rg * 4 + rr][d4 * 4];
                sa[rr][0] = v.x; sa[rr][1] = v.y; sa[rr][2] = v.z; sa[rr][3] = v.w;
            }
            #pragma unroll
            for (int j = 0; j < 4; ++j) {
                const int d = d4 * 4 + j;
                float4 wq = *(const float4*)&Wq[d * EMB + e0];
                float4 wk = *(const float4*)&Wk[d * EMB + e0];
                #pragma unroll
                for (int rr = 0; rr < 4; ++rr) {
                    float s = sa[rr][j];
                    accq[rr][0] += s * wq.x; accq[rr][1] += s * wq.y;
                    accq[rr][2] += s * wq.z; accq[rr][3] += s * wq.w;
                    acck[rr][0] += s * wk.x; acck[rr][1] += s * wk.y;
                    acck[rr][2] += s * wk.z; acck[rr][3] += s * wk.w;
                }
            }
        }
        #pragma unroll
        for (int rr = 0; rr < 4; ++rr) {
            int row = rg * 4 + rr;
            if (row < SEQL) {
                sQ[row][e0]     = 1.f / (1.f + __expf(-accq[rr][0]));
                sQ[row][e0 + 1] = 1.f / (1.f + __expf(-accq[rr][1]));
                sQ[row][e0 + 2] = 1.f / (1.f + __expf(-accq[rr][2]));
                sQ[row][e0 + 3] = 1.f / (1.f + __expf(-accq[rr][3]));
                sK[row][e0]     = 1.f / (1.f + __expf(-acck[rr][0]));
                sK[row][e0 + 1] = 1.f / (1.f + __expf(-acck[rr][1]));
                sK[row][e0 + 2] = 1.f / (1.f + __expf(-acck[rr][2]));
                sK[row][e0 + 3] = 1.f / (1.f + __expf(-acck[rr][3]));
            }
        }
    }
    __syncthreads();

    // scores: alpha partials, 4 threads per l
    const float inv_sqrt_d = rsqrtf((float)EMB);
    if (t < 200) {
        const int l = t >> 2;
        const int m0 = t & 3;
        float partial = 0.f;
        if (s_mask[l] != 0.f) {
            for (int m = m0; m < SEQL; m += 4) {
                if (m == l || s_mask[m] == 0.f) continue;
                float dot = 0.f;
                for (int d4 = 0; d4 < EMB / 4; ++d4) {
                    float4 a = *(const float4*)&sQ[l][d4 * 4];
                    float4 c = *(const float4*)&sK[m][d4 * 4];
                    dot += a.x * c.x + a.y * c.y + a.z * c.z + a.w * c.w;
                }
                partial += inv_sqrt_d / (1.f + __expf(-dot));
            }
        }
        s_part[l][m0] = partial;
    }
    __syncthreads();

    // masked softmax over l (wave 0)
    if (t < 64) {
        float slen = (float)session_len[b];
        float a = -1e30f;
        if (t < SEQL && s_mask[t] > 0.f)
            a = (s_part[t][0] + s_part[t][1] + s_part[t][2] + s_part[t][3]) / slen;
        float mx = a;
        for (int o = 32; o > 0; o >>= 1) mx = fmaxf(mx, __shfl_xor(mx, o));
        float ex = __expf(a - mx);
        float sm = ex;
        for (int o = 32; o > 0; o >>= 1) sm += __shfl_xor(sm, o);
        if (t < SEQL) s_beta[t] = ex / sm;
    }
    __syncthreads();

    // pooled output
    if (t < EMB) {
        float h = 0.f;
        for (int l = 0; l < SEQL; ++l) h += s_beta[l] * s_seq[l][t];
        seq_h[b * EMB + t] = h;
        acc2[b * EMB + t] = h;
    }
}

// ---------------- DA = D @ A  (32x32 LDS-tiled) ----------------------------
__global__ __launch_bounds__(256) void gemm_DA(
    const float* __restrict__ D, const float* __restrict__ A,
    float* __restrict__ DA)
{
    __shared__ float sD[32][33];
    __shared__ float sA[32][33];
    const int tx = threadIdx.x & 15;
    const int ty = threadIdx.x >> 4;
    const int i0 = blockIdx.y * 32;
    const int j0 = blockIdx.x * 32;
    float a00 = 0.f, a01 = 0.f, a10 = 0.f, a11 = 0.f;
    for (int k0 = 0; k0 < BATCH; k0 += 32) {
        for (int idx = threadIdx.x; idx < 1024; idx += 256) {
            int r = idx >> 5, c = idx & 31;
            sD[r][c] = D[(i0 + r) * BATCH + k0 + c];
            sA[r][c] = A[(k0 + r) * BATCH + j0 + c];
        }
        __syncthreads();
        #pragma unroll 8
        for (int kk = 0; kk < 32; ++kk) {
            float d0 = sD[2 * ty][kk], d1 = sD[2 * ty + 1][kk];
            float b0 = sA[kk][2 * tx], b1 = sA[kk][2 * tx + 1];
            a00 += d0 * b0; a01 += d0 * b1;
            a10 += d1 * b0; a11 += d1 * b1;
        }
        __syncthreads();
    }
    DA[(i0 + 2 * ty) * BATCH + j0 + 2 * tx] = a00;
    DA[(i0 + 2 * ty) * BATCH + j0 + 2 * tx + 1] = a01;
    DA[(i0 + 2 * ty + 1) * BATCH + j0 + 2 * tx] = a10;
    DA[(i0 + 2 * ty + 1) * BATCH + j0 + 2 * tx + 1] = a11;
}

// ---------------- t = s @ W^T ----------------------------------------------
__global__ __launch_bounds__(128) void sess_linear(
    const float* __restrict__ s, const float* __restrict__ W,
    float* __restrict__ t)
{
    __shared__ float s_row[EMB];
    int b = blockIdx.x;
    int e = threadIdx.x;
    if (e < EMB) s_row[e] = s[b * EMB + e];
    __syncthreads();
    if (e >= EMB) return;
    float acc = 0.f;
    for (int d = 0; d < EMB; ++d) acc += s_row[d] * W[e * EMB + d];
    t[b * EMB + e] = acc;
}

// ---------------- s = DA @ t; acc2 += s/||s||; last: out = acc2/3 ----------
__global__ __launch_bounds__(128) void sess_prop(
    const float* __restrict__ DA, const float* __restrict__ t,
    float* __restrict__ s_out, float* __restrict__ acc2,
    float* __restrict__ out, int is_last)
{
    __shared__ float s_da[BATCH];
    __shared__ float s_sq[128];
    int b = blockIdx.x;
    int e = threadIdx.x;
    for (int k = e; k < BATCH; k += 128) s_da[k] = DA[b * BATCH + k];
    __syncthreads();

    float v = 0.f;
    if (e < EMB) {
        for (int k = 0; k < BATCH; ++k) v += s_da[k] * t[k * EMB + e];
    }
    s_sq[e] = (e < EMB) ? v * v : 0.f;
    __syncthreads();
    for (int off = 64; off > 0; off >>= 1) {
        if (e < off) s_sq[e] += s_sq[e + off];
        __syncthreads();
    }
    float nrm = fmaxf(sqrtf(s_sq[0]), 1e-12f);
    if (e < EMB) {
        float a = acc2[b * EMB + e] + v / nrm;
        acc2[b * EMB + e] = a;
        s_out[b * EMB + e] = v;
        if (is_last) out[b * EMB + e] = a * (1.f / 3.f);
    }
}

extern "C" void kernel_launch(void* const* d_in, const int* in_sizes, int n_in,
                              void* d_out, int out_size, void* d_ws, size_t ws_size,
                              hipStream_t stream)
{
    (void)in_sizes; (void)n_in; (void)out_size; (void)ws_size;

    const float* embedding    = (const float*)d_in[0];
    const float* adj_vals     = (const float*)d_in[1];
    const float* W_q          = (const float*)d_in[2];
    const float* W_k          = (const float*)d_in[3];
    const float* w_sess       = (const float*)d_in[4];
    const float* D            = (const float*)d_in[5];
    const float* A            = (const float*)d_in[6];
    const int*   adj_rows     = (const int*)d_in[7];
    const int*   adj_cols     = (const int*)d_in[8];
    const int*   session_item = (const int*)d_in[9];
    const int*   session_len  = (const int*)d_in[10];
    const float* mask         = (const float*)d_in[11];
    float* out = (float*)d_out;

    // ---- workspace layout ----
    unsigned short* ebf0 = (unsigned short*)d_ws;                 // 3 x 12.8M ushort (padded)
    unsigned short* ebf1 = ebf0 + (size_t)N_NODE * EMBP;
    unsigned short* ebf2 = ebf1 + (size_t)N_NODE * EMBP;
    float* DAb       = (float*)(ebf2 + (size_t)N_NODE * EMBP);    // 8B-aligned
    float* seqh      = DAb  + (size_t)BATCH * BATCH;
    float* acc2      = seqh + (size_t)BATCH * EMB;
    float* tbuf      = acc2 + (size_t)BATCH * EMB;
    float* sbuf      = tbuf + (size_t)BATCH * EMB;
    int*   counts    = (int*)(sbuf + (size_t)BATCH * EMB);
    int*   row_start = counts + N_NODE;
    int*   needed    = row_start + N_NODE;                        // needed+bcur adjacent
    int*   bcur      = needed + N_NODE;                           // NBUCK, pad 2048
    int2*  csr_cv    = (int2*)(bcur + 2048);                      // NBUCK*BUCK_CAP = 14.4 MB
    uint2* staged    = (uint2*)(csr_cv + (size_t)NBUCK * BUCK_CAP); // 14.4 MB

    // one memset covers needed + bcur (adjacent)
    hipMemsetAsync(needed, 0, (N_NODE + 2048) * sizeof(int), stream);

    // ---- prep: padded bf16 table + mark_needed (fused) ----
    prep<<<N_NODE * 32 / 256, 256, 0, stream>>>(embedding, ebf0,
                                                session_item, needed);

    // ---- CSR build phase 1: bin edges into 256-row buckets ----
    edge_bin<<<P1_BLOCKS, 1024, 0, stream>>>(adj_rows, adj_cols, adj_vals,
                                             bcur, staged);

    // ---- fused: per-bucket sort + csr emit + hyperconv layer 1 ----
    bucket_csr_spmm<<<NBUCK, 1024, 0, stream>>>(staged, bcur, ebf0, ebf1,
                                                csr_cv, row_start, counts);

    // ---- hyperconv layer 2: only rows attention reads ----
    spmm_bf16<<<N_NODE / 8, 256, 0, stream>>>(ebf1, csr_cv, row_start, counts,
                                              needed, ebf2);

    // ---- fused attention (gather + proj + scores + softmax + pool) ----
    attn_fused<<<BATCH, 256, 0, stream>>>(embedding, ebf1, ebf2, session_item,
                                          W_q, W_k, session_len, mask,
                                          seqh, acc2);

    // ---- session graph ----
    gemm_DA<<<dim3(16, 16), 256, 0, stream>>>(D, A, DAb);
    sess_linear<<<BATCH, 128, 0, stream>>>(seqh, w_sess + 0 * EMB * EMB, tbuf);
    sess_prop  <<<BATCH, 128, 0, stream>>>(DAb, tbuf, sbuf, acc2, out, 0);
    sess_linear<<<BATCH, 128, 0, stream>>>(sbuf, w_sess + 1 * EMB * EMB, tbuf);
    sess_prop  <<<BATCH, 128, 0, stream>>>(DAb, tbuf, sbuf, acc2, out, 1);
}

// Round 12
// 363.154 us; speedup vs baseline: 1.1954x; 1.0585x over previous
//
#include <hip/hip_runtime.h>

#define N_NODE 100000
#define EMB 112
#define EMBP 128                      // padded bf16 row: 256 B, line-aligned
#define BATCH 512
#define SEQL 50
#define NNZ 1600000
#define NROWS (BATCH * SEQL)

#define BROWS 256                     // rows per bucket
#define NBUCK ((N_NODE + BROWS - 1) / BROWS)      // 391
#define BUCK_CAP 4608                 // mean 4096, sd 64 -> 8 sigma headroom
#define TILE_E 6250                   // 256 blocks x 1024 threads, exact
#define P1_BLOCKS 256

__device__ __forceinline__ float bf2f(unsigned short u) {
    return __uint_as_float((unsigned)u << 16);
}
__device__ __forceinline__ unsigned short f2bf(float f) {
    unsigned u = __float_as_uint(f);
    return (unsigned short)((u + 0x7FFF + ((u >> 16) & 1)) >> 16);   // RNE
}

// ---------------- prep: fp32 -> padded bf16 table --------------------------
__global__ __launch_bounds__(256) void prep(
    const float* __restrict__ in, unsigned short* __restrict__ out)
{
    int i = blockIdx.x * 256 + threadIdx.x;
    int r = i >> 5, c = i & 31;
    ushort4 o; o.x = 0; o.y = 0; o.z = 0; o.w = 0;
    if (c < 28) {
        float4 v = ((const float4*)in)[r * 28 + c];
        o.x = f2bf(v.x); o.y = f2bf(v.y); o.z = f2bf(v.z); o.w = f2bf(v.w);
    }
    ((ushort4*)out)[i] = o;
}

// ---- phase 1: block-aggregated binning into 256-row bucket regions --------
__global__ __launch_bounds__(1024) void edge_bin(
    const int* __restrict__ rows, const int* __restrict__ cols,
    const float* __restrict__ vals,
    int* __restrict__ bcur, uint2* __restrict__ staged)
{
    __shared__ int hist[NBUCK];
    const int t = threadIdx.x;
    const int e0 = blockIdx.x * TILE_E;
    const int e1 = e0 + TILE_E;

    for (int i = t; i < NBUCK; i += 1024) hist[i] = 0;
    __syncthreads();
    for (int e = e0 + t; e < e1; e += 1024)
        atomicAdd(&hist[rows[e] >> 8], 1);
    __syncthreads();
    for (int i = t; i < NBUCK; i += 1024) {
        int c = hist[i];
        hist[i] = (c > 0) ? atomicAdd(&bcur[i], c) : 0;
    }
    __syncthreads();
    for (int e = e0 + t; e < e1; e += 1024) {
        int r = rows[e];
        int b = r >> 8;
        int k = atomicAdd(&hist[b], 1);
        uint2 s;
        s.x = ((unsigned)(r & 255) << 24) | (unsigned)cols[e];
        s.y = __float_as_uint(vals[e]);
        staged[(size_t)b * BUCK_CAP + k] = s;
    }
}

// ---- fused: bucket-local sort (LDS) + csr emit + spmm layer 1 -------------
__global__ __launch_bounds__(1024) void bucket_csr_spmm(
    const uint2* __restrict__ staged, const int* __restrict__ bcur,
    const unsigned short* __restrict__ src, unsigned short* __restrict__ dst,
    int2* __restrict__ csr_cv, int* __restrict__ row_start,
    int* __restrict__ counts)
{
    __shared__ uint2 s_sorted[BUCK_CAP];
    __shared__ int cnt[BROWS];
    __shared__ int sc[BROWS];
    __shared__ int cur[BROWS];

    const int b = blockIdx.x;
    const int t = threadIdx.x;
    const int n = bcur[b];
    const size_t base = (size_t)b * BUCK_CAP;
    const int r0 = b << 8;

    if (t < BROWS) cnt[t] = 0;
    __syncthreads();
    for (int i = t; i < n; i += 1024)
        atomicAdd(&cnt[staged[base + i].x >> 24], 1);
    __syncthreads();

    if (t < BROWS) sc[t] = cnt[t];
    __syncthreads();
    for (int o = 1; o < BROWS; o <<= 1) {
        int v = 0;
        if (t < BROWS && t >= o) v = sc[t - o];
        __syncthreads();
        if (t < BROWS) sc[t] += v;
        __syncthreads();
    }
    if (t < BROWS) {
        int excl = sc[t] - cnt[t];
        cur[t] = excl;
        int row = r0 + t;
        if (row < N_NODE) {
            row_start[row] = (int)base + excl;
            counts[row] = cnt[t];
        }
    }
    __syncthreads();

    for (int i = t; i < n; i += 1024) {
        uint2 s = staged[base + i];
        int rl = s.x >> 24;
        int k = atomicAdd(&cur[rl], 1);
        uint2 e;
        e.x = s.x & 0x00FFFFFFu;
        e.y = s.y;
        s_sorted[k] = e;
    }
    __syncthreads();

    for (int i = t; i < n; i += 1024) {
        uint2 e = s_sorted[i];
        int2 cv; cv.x = (int)e.x; cv.y = (int)e.y;
        csr_cv[base + i] = cv;
    }

    // spmm layer 1 for this bucket's 256 rows, edges from LDS
    const int wave = t >> 6;
    const int lane = t & 63;
    const int half = lane >> 5;
    const int hl = lane & 31;
    const int d0 = hl * 4;

    for (int it = 0; it < 8; ++it) {
        int rl = wave * 16 + it * 2 + half;
        int row = r0 + rl;
        bool valid = row < N_NODE;
        int n_r = valid ? cnt[rl] : 0;
        int beg = valid ? (sc[rl] - cnt[rl]) : 0;

        float a0 = 0.f, a1 = 0.f, a2 = 0.f, a3 = 0.f;
        int i = 0;
        for (; i + 8 <= n_r; i += 8) {
            #pragma unroll
            for (int j = 0; j < 8; ++j) {
                uint2 e = s_sorted[beg + i + j];
                float v = __uint_as_float(e.y);
                ushort4 u = *(const ushort4*)(src + (size_t)e.x * EMBP + d0);
                a0 += v * bf2f(u.x);
                a1 += v * bf2f(u.y);
                a2 += v * bf2f(u.z);
                a3 += v * bf2f(u.w);
            }
        }
        for (; i < n_r; ++i) {
            uint2 e = s_sorted[beg + i];
            float v = __uint_as_float(e.y);
            ushort4 u = *(const ushort4*)(src + (size_t)e.x * EMBP + d0);
            a0 += v * bf2f(u.x);
            a1 += v * bf2f(u.y);
            a2 += v * bf2f(u.z);
            a3 += v * bf2f(u.w);
        }
        if (valid) {
            ushort4 o;
            o.x = f2bf(a0); o.y = f2bf(a1); o.z = f2bf(a2); o.w = f2bf(a3);
            *(ushort4*)(dst + (size_t)row * EMBP + d0) = o;
        }
    }
}

// ---------------- fused attention (w/ on-the-fly layer-2) + gemm_DA --------
// blocks [0,512): attention for batch b; blocks [512,768): DA=D@A tiles.
#define APAD 116
struct AttnSmem {
    float s_seq[52][APAD];
    float sQ[SEQL][APAD];
    float sK[SEQL][APAD];
    float s_part[SEQL][4];
    float s_mask[SEQL];
    float s_beta[SEQL];
};
struct GemmSmem {
    float sD[32][33];
    float sA[32][33];
};
union AttnDaSmem { AttnSmem a; GemmSmem g; };

__global__ __launch_bounds__(256) void attn_da(
    const float* __restrict__ emb0,
    const unsigned short* __restrict__ e1b,
    const int2* __restrict__ csr_cv, const int* __restrict__ row_start,
    const int* __restrict__ counts,
    const int* __restrict__ items,
    const float* __restrict__ Wq, const float* __restrict__ Wk,
    const int* __restrict__ session_len, const float* __restrict__ mask,
    const float* __restrict__ D, const float* __restrict__ A,
    float* __restrict__ DA,
    float* __restrict__ seq_h, float* __restrict__ acc2)
{
    __shared__ AttnDaSmem sm;
    const int t = threadIdx.x;

    if (blockIdx.x >= BATCH) {
        // ---------------- gemm_DA branch ----------------
        const int bid = blockIdx.x - BATCH;
        const int i0 = (bid >> 4) * 32;
        const int j0 = (bid & 15) * 32;
        const int tx = t & 15;
        const int ty = t >> 4;
        float a00 = 0.f, a01 = 0.f, a10 = 0.f, a11 = 0.f;
        for (int k0 = 0; k0 < BATCH; k0 += 32) {
            for (int idx = t; idx < 1024; idx += 256) {
                int r = idx >> 5, c = idx & 31;
                sm.g.sD[r][c] = D[(i0 + r) * BATCH + k0 + c];
                sm.g.sA[r][c] = A[(k0 + r) * BATCH + j0 + c];
            }
            __syncthreads();
            #pragma unroll 8
            for (int kk = 0; kk < 32; ++kk) {
                float d0 = sm.g.sD[2 * ty][kk], d1 = sm.g.sD[2 * ty + 1][kk];
                float b0 = sm.g.sA[kk][2 * tx], b1 = sm.g.sA[kk][2 * tx + 1];
                a00 += d0 * b0; a01 += d0 * b1;
                a10 += d1 * b0; a11 += d1 * b1;
            }
            __syncthreads();
        }
        DA[(i0 + 2 * ty) * BATCH + j0 + 2 * tx] = a00;
        DA[(i0 + 2 * ty) * BATCH + j0 + 2 * tx + 1] = a01;
        DA[(i0 + 2 * ty + 1) * BATCH + j0 + 2 * tx] = a10;
        DA[(i0 + 2 * ty + 1) * BATCH + j0 + 2 * tx + 1] = a11;
        return;
    }

    // ---------------- attention branch ----------------
    const int b = blockIdx.x;

    // phase 1: gather seq rows; emb2 computed on the fly from CSR + emb1
    const int hw = t >> 5;        // 0..7 half-waves
    const int hl = t & 31;
    const int d0 = hl * 4;
    for (int l = hw; l < 52; l += 8) {
        float a0 = 0.f, a1 = 0.f, a2 = 0.f, a3 = 0.f;
        int g = (l < SEQL) ? items[b * SEQL + l] : 0;
        if (g > 0) {
            const int r = g - 1;
            const int n = counts[r];
            const int beg = row_start[r];
            int i = 0;
            for (; i + 8 <= n; i += 8) {
                #pragma unroll
                for (int j = 0; j < 8; ++j) {
                    int2 cv = csr_cv[beg + i + j];
                    float v = __int_as_float(cv.y);
                    ushort4 u = *(const ushort4*)(e1b + (size_t)cv.x * EMBP + d0);
                    a0 += v * bf2f(u.x);
                    a1 += v * bf2f(u.y);
                    a2 += v * bf2f(u.z);
                    a3 += v * bf2f(u.w);
                }
            }
            for (; i < n; ++i) {
                int2 cv = csr_cv[beg + i];
                float v = __int_as_float(cv.y);
                ushort4 u = *(const ushort4*)(e1b + (size_t)cv.x * EMBP + d0);
                a0 += v * bf2f(u.x);
                a1 += v * bf2f(u.y);
                a2 += v * bf2f(u.z);
                a3 += v * bf2f(u.w);
            }
            // + emb1 self + emb0 self
            ushort4 u1 = *(const ushort4*)(e1b + (size_t)r * EMBP + d0);
            a0 += bf2f(u1.x); a1 += bf2f(u1.y); a2 += bf2f(u1.z); a3 += bf2f(u1.w);
            if (hl < 28) {
                float4 v0 = *(const float4*)(emb0 + (size_t)r * EMB + d0);
                a0 += v0.x; a1 += v0.y; a2 += v0.z; a3 += v0.w;
            }
            a0 *= (1.f / 3.f); a1 *= (1.f / 3.f);
            a2 *= (1.f / 3.f); a3 *= (1.f / 3.f);
        }
        if (hl < 28) {
            float4 w; w.x = a0; w.y = a1; w.z = a2; w.w = a3;
            *(float4*)&sm.a.s_seq[l][d0] = w;
        }
    }
    if (t < SEQL) sm.a.s_mask[t] = mask[b * SEQL + t];
    __syncthreads();

    // phase 2: Q/K projection, 4x4 register tiles (13 row groups x 28 quads)
    for (int u = t; u < 13 * 28; u += 256) {
        const int rg = u / 28;
        const int e0 = (u - rg * 28) * 4;
        float accq[4][4] = {{0.f}}, acck[4][4] = {{0.f}};
        for (int d4 = 0; d4 < 28; ++d4) {
            float sa[4][4];
            #pragma unroll
            for (int rr = 0; rr < 4; ++rr) {
                float4 v = *(const float4*)&sm.a.s_seq[rg * 4 + rr][d4 * 4];
                sa[rr][0] = v.x; sa[rr][1] = v.y; sa[rr][2] = v.z; sa[rr][3] = v.w;
            }
            #pragma unroll
            for (int j = 0; j < 4; ++j) {
                const int d = d4 * 4 + j;
                float4 wq = *(const float4*)&Wq[d * EMB + e0];
                float4 wk = *(const float4*)&Wk[d * EMB + e0];
                #pragma unroll
                for (int rr = 0; rr < 4; ++rr) {
                    float s = sa[rr][j];
                    accq[rr][0] += s * wq.x; accq[rr][1] += s * wq.y;
                    accq[rr][2] += s * wq.z; accq[rr][3] += s * wq.w;
                    acck[rr][0] += s * wk.x; acck[rr][1] += s * wk.y;
                    acck[rr][2] += s * wk.z; acck[rr][3] += s * wk.w;
                }
            }
        }
        #pragma unroll
        for (int rr = 0; rr < 4; ++rr) {
            int row = rg * 4 + rr;
            if (row < SEQL) {
                sm.a.sQ[row][e0]     = 1.f / (1.f + __expf(-accq[rr][0]));
                sm.a.sQ[row][e0 + 1] = 1.f / (1.f + __expf(-accq[rr][1]));
                sm.a.sQ[row][e0 + 2] = 1.f / (1.f + __expf(-accq[rr][2]));
                sm.a.sQ[row][e0 + 3] = 1.f / (1.f + __expf(-accq[rr][3]));
                sm.a.sK[row][e0]     = 1.f / (1.f + __expf(-acck[rr][0]));
                sm.a.sK[row][e0 + 1] = 1.f / (1.f + __expf(-acck[rr][1]));
                sm.a.sK[row][e0 + 2] = 1.f / (1.f + __expf(-acck[rr][2]));
                sm.a.sK[row][e0 + 3] = 1.f / (1.f + __expf(-acck[rr][3]));
            }
        }
    }
    __syncthreads();

    // phase 3: score partials
    const float inv_sqrt_d = rsqrtf((float)EMB);
    if (t < 200) {
        const int l = t >> 2;
        const int m0 = t & 3;
        float partial = 0.f;
        if (sm.a.s_mask[l] != 0.f) {
            for (int m = m0; m < SEQL; m += 4) {
                if (m == l || sm.a.s_mask[m] == 0.f) continue;
                float dot = 0.f;
                for (int d4 = 0; d4 < EMB / 4; ++d4) {
                    float4 a = *(const float4*)&sm.a.sQ[l][d4 * 4];
                    float4 c = *(const float4*)&sm.a.sK[m][d4 * 4];
                    dot += a.x * c.x + a.y * c.y + a.z * c.z + a.w * c.w;
                }
                partial += inv_sqrt_d / (1.f + __expf(-dot));
            }
        }
        sm.a.s_part[l][m0] = partial;
    }
    __syncthreads();

    // phase 4: masked softmax (wave 0)
    if (t < 64) {
        float slen = (float)session_len[b];
        float a = -1e30f;
        if (t < SEQL && sm.a.s_mask[t] > 0.f)
            a = (sm.a.s_part[t][0] + sm.a.s_part[t][1] +
                 sm.a.s_part[t][2] + sm.a.s_part[t][3]) / slen;
        float mx = a;
        for (int o = 32; o > 0; o >>= 1) mx = fmaxf(mx, __shfl_xor(mx, o));
        float ex = __expf(a - mx);
        float sm_ = ex;
        for (int o = 32; o > 0; o >>= 1) sm_ += __shfl_xor(sm_, o);
        if (t < SEQL) sm.a.s_beta[t] = ex / sm_;
    }
    __syncthreads();

    // phase 5: pooled output
    if (t < EMB) {
        float h = 0.f;
        for (int l = 0; l < SEQL; ++l) h += sm.a.s_beta[l] * sm.a.s_seq[l][t];
        seq_h[b * EMB + t] = h;
        acc2[b * EMB + t] = h;
    }
}

// ---------------- fused session layer: s_new = DA @ (s @ W^T), norm, acc ---
// Per block b: u = DA[b,:] @ s  (coalesced L2 reads), v = u @ W^T, normalize.
__global__ __launch_bounds__(128) void sess_fused(
    const float* __restrict__ DA, const float* __restrict__ s_in,
    const float* __restrict__ W,
    float* __restrict__ s_out, float* __restrict__ acc2,
    float* __restrict__ out, int is_last)
{
    __shared__ float da[BATCH];
    __shared__ float u[EMB];
    __shared__ float red[128];
    const int b = blockIdx.x;
    const int e = threadIdx.x;

    for (int k = e; k < BATCH; k += 128) da[k] = DA[b * BATCH + k];
    __syncthreads();

    float uu = 0.f;
    if (e < EMB) {
        #pragma unroll 8
        for (int k = 0; k < BATCH; ++k) uu += da[k] * s_in[k * EMB + e];
        u[e] = uu;
    }
    __syncthreads();

    float v = 0.f;
    if (e < EMB) {
        #pragma unroll 8
        for (int d = 0; d < EMB; ++d) v += u[d] * W[e * EMB + d];
    }
    red[e] = (e < EMB) ? v * v : 0.f;
    __syncthreads();
    for (int off = 64; off > 0; off >>= 1) {
        if (e < off) red[e] += red[e + off];
        __syncthreads();
    }
    float nrm = fmaxf(sqrtf(red[0]), 1e-12f);
    if (e < EMB) {
        float a = acc2[b * EMB + e] + v / nrm;
        acc2[b * EMB + e] = a;
        s_out[b * EMB + e] = v;
        if (is_last) out[b * EMB + e] = a * (1.f / 3.f);
    }
}

extern "C" void kernel_launch(void* const* d_in, const int* in_sizes, int n_in,
                              void* d_out, int out_size, void* d_ws, size_t ws_size,
                              hipStream_t stream)
{
    (void)in_sizes; (void)n_in; (void)out_size; (void)ws_size;

    const float* embedding    = (const float*)d_in[0];
    const float* adj_vals     = (const float*)d_in[1];
    const float* W_q          = (const float*)d_in[2];
    const float* W_k          = (const float*)d_in[3];
    const float* w_sess       = (const float*)d_in[4];
    const float* D            = (const float*)d_in[5];
    const float* A            = (const float*)d_in[6];
    const int*   adj_rows     = (const int*)d_in[7];
    const int*   adj_cols     = (const int*)d_in[8];
    const int*   session_item = (const int*)d_in[9];
    const int*   session_len  = (const int*)d_in[10];
    const float* mask         = (const float*)d_in[11];
    float* out = (float*)d_out;

    // ---- workspace layout ----
    unsigned short* ebf0 = (unsigned short*)d_ws;                 // 2 x 12.8M ushort
    unsigned short* ebf1 = ebf0 + (size_t)N_NODE * EMBP;
    float* DAb       = (float*)(ebf1 + (size_t)N_NODE * EMBP);    // 8B-aligned
    float* seqh      = DAb  + (size_t)BATCH * BATCH;
    float* acc2      = seqh + (size_t)BATCH * EMB;
    float* sbuf      = acc2 + (size_t)BATCH * EMB;
    int*   counts    = (int*)(sbuf + (size_t)BATCH * EMB);
    int*   row_start = counts + N_NODE;
    int*   bcur      = row_start + N_NODE;                        // NBUCK, pad 2048
    int2*  csr_cv    = (int2*)(bcur + 2048);                      // 14.4 MB
    uint2* staged    = (uint2*)(csr_cv + (size_t)NBUCK * BUCK_CAP); // 14.4 MB

    hipMemsetAsync(bcur, 0, 2048 * sizeof(int), stream);

    // ---- prep: padded bf16 table ----
    prep<<<N_NODE * 32 / 256, 256, 0, stream>>>(embedding, ebf0);

    // ---- CSR build phase 1: bin edges into 256-row buckets ----
    edge_bin<<<P1_BLOCKS, 1024, 0, stream>>>(adj_rows, adj_cols, adj_vals,
                                             bcur, staged);

    // ---- fused: per-bucket sort + csr emit + hyperconv layer 1 ----
    bucket_csr_spmm<<<NBUCK, 1024, 0, stream>>>(staged, bcur, ebf0, ebf1,
                                                csr_cv, row_start, counts);

    // ---- fused attention (layer-2 on the fly) + gemm_DA ----
    attn_da<<<BATCH + 256, 256, 0, stream>>>(embedding, ebf1, csr_cv, row_start,
                                             counts, session_item, W_q, W_k,
                                             session_len, mask, D, A, DAb,
                                             seqh, acc2);

    // ---- session graph: 2 fused layers ----
    sess_fused<<<BATCH, 128, 0, stream>>>(DAb, seqh, w_sess + 0 * EMB * EMB,
                                          sbuf, acc2, out, 0);
    sess_fused<<<BATCH, 128, 0, stream>>>(DAb, sbuf, w_sess + 1 * EMB * EMB,
                                          sbuf, acc2, out, 1);
}